// Round 6
// baseline (137.365 us; speedup 1.0000x reference)
//
#include <hip/hip_runtime.h>
#include <hip/hip_bf16.h>
#include <cstdint>

// TT-linear: y[4096,4096] = x[4096,1024] @ W[1024,4096] + bias
// Kernel 1 (prep): fused x->bf16 convert + W^T reconstruction from TT cores (unchanged).
// Kernel 2 (tt_gemm): Round-6 restructure for 2 blocks/CU:
//   BM=256, BN=128, BK=32, 8 waves (2Mx4N, wave out 128x32), 3-slot LDS ring
//   (A 16KB + B 8KB per slot = 72 KB total -> 2 blocks/CU; launch_bounds(512,4)
//   caps VGPR<=128 so both blocks are resident). Rationale (R5 counters):
//   1 block/CU left the 64MB C-write burst (~12us) fully exposed and barrier
//   skew unabsorbed (in-loop util 46%). Second resident block overlaps both.
//   All verified R5 mechanisms kept: 64-B LDS rows / 4x16B chunks, swizzle
//   involution (x>>1)&3 (0 conflicts), phase = {reads; stage; bar; setprio
//   MFMA; bar}, counted vmcnt (ring: stage kt+2 during kt, vmcnt(3) at tile
//   end gates kt+1; never 0 mid-loop).

typedef __bf16 bf16x8 __attribute__((ext_vector_type(8)));
typedef float f32x4 __attribute__((ext_vector_type(4)));

__device__ __forceinline__ void g2lds16(const void* g, void* l) {
    __builtin_amdgcn_global_load_lds(
        (const __attribute__((address_space(1))) void*)g,
        (__attribute__((address_space(3))) void*)l,
        16, 0, 0);
}

// --------------------------------------------------------------------- prep
__global__ __launch_bounds__(256) void prep(
    const float* __restrict__ x, __bf16* __restrict__ xb,
    const float* __restrict__ c0, const float* __restrict__ c1,
    const float* __restrict__ c2, const float* __restrict__ c3,
    __bf16* __restrict__ wt) {
    const int b = blockIdx.x;
    const int t = threadIdx.x;
    if (b < 2048) {
        const int i = (b * 256 + t) * 8;
        float4 a0 = *(const float4*)(x + i);
        float4 a1 = *(const float4*)(x + i + 4);
        bf16x8 o;
        o[0] = (__bf16)a0.x; o[1] = (__bf16)a0.y; o[2] = (__bf16)a0.z; o[3] = (__bf16)a0.w;
        o[4] = (__bf16)a1.x; o[5] = (__bf16)a1.y; o[6] = (__bf16)a1.z; o[7] = (__bf16)a1.w;
        *(bf16x8*)(xb + i) = o;
        return;
    }
    __shared__ float t12[4][16];     // [wave][r2]
    __shared__ float t123[4][512];   // [wave][m3*8+n3][r3]
    __shared__ float c3s[512];       // [(r3*4+m4)*8+n4]
    #pragma unroll
    for (int i = t; i < 512; i += 256) c3s[i] = c3[i];
    const int s = t >> 6;
    const int lane = t & 63;
    const int g = (b - 2048) * 4 + s;
    const int m1 = g >> 9, n1 = (g >> 6) & 7, m2 = (g >> 3) & 7, n2 = g & 7;
    __syncthreads();
    if (lane < 16) {
        const int r2 = lane;
        float sum = 0.f;
        #pragma unroll
        for (int r1 = 0; r1 < 16; ++r1)
            sum += c0[(m1 * 8 + n1) * 16 + r1] * c1[((r1 * 8 + m2) * 8 + n2) * 16 + r2];
        t12[s][r2] = sum;
    }
    __syncthreads();
    #pragma unroll
    for (int idx = lane; idx < 512; idx += 64) {
        const int m3 = idx >> 7, n3 = (idx >> 4) & 7, r3 = idx & 15;
        float sum = 0.f;
        #pragma unroll
        for (int r2 = 0; r2 < 16; ++r2)
            sum += t12[s][r2] * c2[((r2 * 4 + m3) * 8 + n3) * 16 + r3];
        t123[s][(m3 * 8 + n3) * 16 + r3] = sum;
    }
    __syncthreads();
    const int n3 = lane >> 3, n4 = lane & 7;
    const int n = ((n1 * 8 + n2) * 8 + n3) * 8 + n4;
    const int kbase = (m1 * 8 + m2) * 16;
    float v[16];
    #pragma unroll
    for (int e = 0; e < 16; ++e) v[e] = 0.f;
    #pragma unroll
    for (int m3 = 0; m3 < 4; ++m3) {
        #pragma unroll
        for (int r3 = 0; r3 < 16; ++r3) {
            const float tv = t123[s][(m3 * 8 + n3) * 16 + r3];
            #pragma unroll
            for (int m4 = 0; m4 < 4; ++m4)
                v[m3 * 4 + m4] += tv * c3s[(r3 * 4 + m4) * 8 + n4];
        }
    }
    bf16x8 lo, hi;
    #pragma unroll
    for (int e = 0; e < 8; ++e) { lo[e] = (__bf16)v[e]; hi[e] = (__bf16)v[8 + e]; }
    *(bf16x8*)(wt + (size_t)n * 1024 + kbase)     = lo;
    *(bf16x8*)(wt + (size_t)n * 1024 + kbase + 8) = hi;
}

// -------------------------------------------------------------- GEMM + bias
// C[4096,4096] f32 = A[4096,1024] bf16 @ Bt[4096,1024]^T bf16 + bias
// Geometry: BM=256, BN=128, BK=32 (32 K-tiles), 8 waves 2Mx4N (wave 128x32),
// 512 threads, grid 512 (16 bm x 32 bn), 2 blocks/CU.
// LDS ring: sA[3][256x32] + sB[3][128x32] = 72 KB; tile kt in slot kt%3,
// staged during tile kt-2 (A at P0, B at P1). End-of-tile vmcnt(3): 6
// outstanding (kt+1:3, kt+2:3), waits oldest 3 => kt+1 fully in LDS.
// Slot-reuse safety: ST(kt+2) targets slot(kt-1), whose reads all retired
// before the end-of-(kt-1) barrier (lgkm before MFMA), and ST issues after it.
// Swizzle: 64-B rows, 4 x 16B chunks, phys = logical ^ ((row>>1)&3) both
// sides (R5-verified: 0 conflicts). global_load_lds dests stay linear.

#define SCHED() __builtin_amdgcn_sched_barrier(0)
#define BAR()  do { SCHED(); __builtin_amdgcn_s_barrier(); SCHED(); } while (0)
#define WAITVM(n) do { SCHED(); asm volatile("s_waitcnt vmcnt(" #n ")"); SCHED(); } while (0)

__global__ __launch_bounds__(512, 4) void tt_gemm(
    const __bf16* __restrict__ A, const __bf16* __restrict__ B,
    const float* __restrict__ bias, float* __restrict__ C) {
    constexpr int K = 1024, N = 4096;
    constexpr int NKT = 32;                  // K-tiles of 32
    __shared__ __bf16 sA[3][256 * 32];       // 3 x 16 KB
    __shared__ __bf16 sB[3][128 * 32];       // 3 x 8 KB
    const int t = threadIdx.x;
    const int lane = t & 63;
    const int wave = t >> 6;                 // 0..7
    const int wm = (wave >> 2) * 128;        // 0 / 128   (M range of wave)
    const int wn = (wave & 3) * 32;          // 0..96     (N range of wave)
    const int l15 = lane & 15, lh = lane >> 4;
    const int cOff = ((lh ^ ((l15 >> 1) & 3)) << 4);  // swizzled 16B chunk in 64-B row

    // XCD-aware mapping: 2x4 XCD grid, each XCD owns an 8bm x 8bn patch (bijective)
    const int xcd = blockIdx.x & 7;
    const int lid = blockIdx.x >> 3;         // 0..63
    const int bmo = ((xcd >> 2) * 8 + (lid & 7)) * 256;   // row offset
    const int bno = ((xcd & 3) * 8 + (lid >> 3)) * 128;   // col offset

    // staging: A tile = 1024 chunks of 16B (thread owns t, t+512);
    //          B tile = 512 chunks (thread owns t)
    const int c0i = t, c1i = t + 512;
    const int rA0 = c0i >> 2, rA1 = c1i >> 2;            // A row 0..255
    const int lcA0 = (c0i & 3) ^ ((rA0 >> 1) & 3);       // logical chunk (global)
    const int lcA1 = (c1i & 3) ^ ((rA1 >> 1) & 3);
    const int rB = t >> 2;                               // B row 0..127
    const int lcB = (t & 3) ^ ((rB >> 1) & 3);
    const __bf16* a0p = A + (size_t)(bmo + rA0) * K + lcA0 * 8;
    const __bf16* a1p = A + (size_t)(bmo + rA1) * K + lcA1 * 8;
    const __bf16* bp  = B + (size_t)(bno + rB)  * K + lcB * 8;

#define ST_A(kt, sl) do { \
    g2lds16(a0p + (size_t)(kt) * 32, (char*)&sA[sl][0] + c0i * 16); \
    g2lds16(a1p + (size_t)(kt) * 32, (char*)&sA[sl][0] + c1i * 16); } while (0)
#define ST_B(kt, sl) \
    g2lds16(bp + (size_t)(kt) * 32, (char*)&sB[sl][0] + t * 16)
#define LDA(dst, fi) dst = *(const bf16x8*)((const char*)&sA[s0][0] + (wm + (fi) * 16 + l15) * 64 + cOff)
#define LDB(dst, ni) dst = *(const bf16x8*)((const char*)&sB[s0][0] + (wn + (ni) * 16 + l15) * 64 + cOff)
#define MFMA8(base, afr) do { \
    __builtin_amdgcn_s_setprio(1); \
    _Pragma("unroll") \
    for (int mi = 0; mi < 4; ++mi) \
        _Pragma("unroll") \
        for (int ni = 0; ni < 2; ++ni) \
            acc[(base) + mi][ni] = __builtin_amdgcn_mfma_f32_16x16x32_bf16( \
                afr[mi], bb[ni], acc[(base) + mi][ni], 0, 0, 0); \
    __builtin_amdgcn_s_setprio(0); } while (0)

    f32x4 acc[8][2] = {};

    // prologue: stage tiles 0 (slot0) and 1 (slot1) = 6 loads; oldest 3 = tile 0
    ST_A(0, 0); ST_B(0, 0);
    ST_A(1, 1); ST_B(1, 1);
    WAITVM(3);
    BAR();

    #pragma unroll 1
    for (int kt = 0; kt < NKT; ++kt) {
        const int s0 = kt % 3;
        const int s2 = (kt + 2) % 3;
        bf16x8 aL[4], aH[4], bb[2];
        // ---- P0: frags (m-low) + both B; stage A(kt+2)
        #pragma unroll
        for (int mi = 0; mi < 4; ++mi) LDA(aL[mi], mi);
        #pragma unroll
        for (int ni = 0; ni < 2; ++ni) LDB(bb[ni], ni);
        if (kt < NKT - 2) ST_A(kt + 2, s2);
        BAR();
        MFMA8(0, aL);
        BAR();
        // ---- P1: frags (m-high); stage B(kt+2); counted wait gates kt+1
        #pragma unroll
        for (int mi = 0; mi < 4; ++mi) LDA(aH[mi], 4 + mi);
        if (kt < NKT - 2) ST_B(kt + 2, s2);
        BAR();
        MFMA8(4, aH);
        if (kt < NKT - 2)       { WAITVM(3); }
        else if (kt == NKT - 2) { WAITVM(0); }
        BAR();
    }

    // epilogue: C/D layout col=lane&15, row=(lane>>4)*4+reg (m89-verified);
    // ni-inner: each wave emits 128B contiguous per row
    float bv[2];
    #pragma unroll
    for (int ni = 0; ni < 2; ++ni) bv[ni] = bias[bno + wn + ni * 16 + l15];
    #pragma unroll
    for (int mi = 0; mi < 8; ++mi) {
        #pragma unroll
        for (int r = 0; r < 4; ++r) {
            const int row = bmo + wm + mi * 16 + lh * 4 + r;
            float* crow = C + (size_t)row * N + bno + wn + l15;
            crow[0]  = acc[mi][0][r] + bv[0];
            crow[16] = acc[mi][1][r] + bv[1];
        }
    }
#undef ST_A
#undef ST_B
#undef LDA
#undef LDB
#undef MFMA8
}

extern "C" void kernel_launch(void* const* d_in, const int* in_sizes, int n_in,
                              void* d_out, int out_size, void* d_ws, size_t ws_size,
                              hipStream_t stream) {
    const float* x    = (const float*)d_in[0];
    const float* c0   = (const float*)d_in[1];
    const float* c1   = (const float*)d_in[2];
    const float* c2   = (const float*)d_in[3];
    const float* c3   = (const float*)d_in[4];
    const float* bias = (const float*)d_in[5];
    float* out = (float*)d_out;

    __bf16* xb = (__bf16*)d_ws;                    // 4096*1024 bf16 = 8.39 MB
    __bf16* wt = xb + (size_t)4096 * 1024;         // 4096*1024 bf16 = 8.39 MB

    prep<<<3072, 256, 0, stream>>>(x, xb, c0, c1, c2, c3, wt);
    tt_gemm<<<512, 512, 0, stream>>>(xb, wt, bias, out);
}

// Round 7
// 134.681 us; speedup vs baseline: 1.0199x; 1.0199x over previous
//
#include <hip/hip_runtime.h>
#include <hip/hip_bf16.h>
#include <cstdint>

// TT-linear: y[4096,4096] = x[4096,1024] @ W[1024,4096] + bias
// Kernel 1 (prep): fused x->bf16 convert + W^T reconstruction from TT cores (unchanged).
// Kernel 2 (tt_gemm): Round-7 = R5 geometry (256x256, BK=64, 8 waves 2Mx4N,
//   wave 128x64 -- the LDS-read:MFMA balanced wave tile; R6 proved 128x32 is
//   LDS-pipe-bound) with MINIMAL barriers: 2 per K-tile instead of 8.
//   Hazard audit: (a) staging A/B(kt+2,ks0) writes slot kt&1 ks0, read by this
//   tile's ks0 MFMAs -> ONE mid-tile barrier after them; (b) tile kt+1 readable
//   -> ONE end-of-tile WAITVM(4)+barrier (certifies E1/E2(kt)=A/B(kt+1,ks1)
//   and E3/E4(kt-1)=A/B(kt+1,ks0); leaves E3/E4(kt) in flight -- never drains).
//   Opposite-slot ks1 staging races nothing (readers finished 2 barriers ago).
//   Between barriers waves free-run: compiler interleaves ds_read/MFMA with
//   fine lgkmcnt, waves drift -> reads hide under MFMA across waves.

typedef __bf16 bf16x8 __attribute__((ext_vector_type(8)));
typedef float f32x4 __attribute__((ext_vector_type(4)));

__device__ __forceinline__ void g2lds16(const void* g, void* l) {
    __builtin_amdgcn_global_load_lds(
        (const __attribute__((address_space(1))) void*)g,
        (__attribute__((address_space(3))) void*)l,
        16, 0, 0);
}

// --------------------------------------------------------------------- prep
__global__ __launch_bounds__(256) void prep(
    const float* __restrict__ x, __bf16* __restrict__ xb,
    const float* __restrict__ c0, const float* __restrict__ c1,
    const float* __restrict__ c2, const float* __restrict__ c3,
    __bf16* __restrict__ wt) {
    const int b = blockIdx.x;
    const int t = threadIdx.x;
    if (b < 2048) {
        const int i = (b * 256 + t) * 8;
        float4 a0 = *(const float4*)(x + i);
        float4 a1 = *(const float4*)(x + i + 4);
        bf16x8 o;
        o[0] = (__bf16)a0.x; o[1] = (__bf16)a0.y; o[2] = (__bf16)a0.z; o[3] = (__bf16)a0.w;
        o[4] = (__bf16)a1.x; o[5] = (__bf16)a1.y; o[6] = (__bf16)a1.z; o[7] = (__bf16)a1.w;
        *(bf16x8*)(xb + i) = o;
        return;
    }
    __shared__ float t12[4][16];     // [wave][r2]
    __shared__ float t123[4][512];   // [wave][m3*8+n3][r3]
    __shared__ float c3s[512];       // [(r3*4+m4)*8+n4]
    #pragma unroll
    for (int i = t; i < 512; i += 256) c3s[i] = c3[i];
    const int s = t >> 6;
    const int lane = t & 63;
    const int g = (b - 2048) * 4 + s;
    const int m1 = g >> 9, n1 = (g >> 6) & 7, m2 = (g >> 3) & 7, n2 = g & 7;
    __syncthreads();
    if (lane < 16) {
        const int r2 = lane;
        float sum = 0.f;
        #pragma unroll
        for (int r1 = 0; r1 < 16; ++r1)
            sum += c0[(m1 * 8 + n1) * 16 + r1] * c1[((r1 * 8 + m2) * 8 + n2) * 16 + r2];
        t12[s][r2] = sum;
    }
    __syncthreads();
    #pragma unroll
    for (int idx = lane; idx < 512; idx += 64) {
        const int m3 = idx >> 7, n3 = (idx >> 4) & 7, r3 = idx & 15;
        float sum = 0.f;
        #pragma unroll
        for (int r2 = 0; r2 < 16; ++r2)
            sum += t12[s][r2] * c2[((r2 * 4 + m3) * 8 + n3) * 16 + r3];
        t123[s][(m3 * 8 + n3) * 16 + r3] = sum;
    }
    __syncthreads();
    const int n3 = lane >> 3, n4 = lane & 7;
    const int n = ((n1 * 8 + n2) * 8 + n3) * 8 + n4;
    const int kbase = (m1 * 8 + m2) * 16;
    float v[16];
    #pragma unroll
    for (int e = 0; e < 16; ++e) v[e] = 0.f;
    #pragma unroll
    for (int m3 = 0; m3 < 4; ++m3) {
        #pragma unroll
        for (int r3 = 0; r3 < 16; ++r3) {
            const float tv = t123[s][(m3 * 8 + n3) * 16 + r3];
            #pragma unroll
            for (int m4 = 0; m4 < 4; ++m4)
                v[m3 * 4 + m4] += tv * c3s[(r3 * 4 + m4) * 8 + n4];
        }
    }
    bf16x8 lo, hi;
    #pragma unroll
    for (int e = 0; e < 8; ++e) { lo[e] = (__bf16)v[e]; hi[e] = (__bf16)v[8 + e]; }
    *(bf16x8*)(wt + (size_t)n * 1024 + kbase)     = lo;
    *(bf16x8*)(wt + (size_t)n * 1024 + kbase + 8) = hi;
}

// -------------------------------------------------------------- GEMM + bias
// C[4096,4096] f32 = A[4096,1024] bf16 @ Bt[4096,1024]^T bf16 + bias
// Geometry: BM=BN=256, BK=64 (16 K-tiles), 8 waves 2Mx4N (wave 128x64),
// 512 threads, grid 256 (1 block/CU). LDS sA/sB[2 slots][2 ks][256x32] = 128 KB.
// Swizzle: 64-B rows, 4 x 16B chunks, phys = logical ^ ((row>>1)&3) both sides
// (R5-verified: 0 conflicts). global_load_lds destinations stay linear.
// Stage stream per tile kt: half0: A/B(kt+1,ks1) [E1/E2]; half1: A/B(kt+2,ks0)
// [E3/E4]. End-of-tile vmcnt(4): leaves only E3/E4(kt) in flight.

#define SCHED() __builtin_amdgcn_sched_barrier(0)
#define BAR()  do { SCHED(); __builtin_amdgcn_s_barrier(); SCHED(); } while (0)
#define WAITVM(n) do { SCHED(); asm volatile("s_waitcnt vmcnt(" #n ")"); SCHED(); } while (0)

__global__ __launch_bounds__(512, 2) void tt_gemm(
    const __bf16* __restrict__ A, const __bf16* __restrict__ B,
    const float* __restrict__ bias, float* __restrict__ C) {
    constexpr int K = 1024, N = 4096;
    constexpr int NKT = 16;                  // K-tiles of 64
    __shared__ __bf16 sA[2][2][256 * 32];    // [slot][ks][16 KB]
    __shared__ __bf16 sB[2][2][256 * 32];
    const int t = threadIdx.x;
    const int lane = t & 63;
    const int wave = t >> 6;                 // 0..7
    const int wm = (wave >> 2) * 128;        // 0 / 128   (M range of wave)
    const int wn = (wave & 3) * 64;          // 0..192    (N range of wave)
    const int l15 = lane & 15, lh = lane >> 4;
    const int cOff = ((lh ^ ((l15 >> 1) & 3)) << 4);  // swizzled 16B chunk in 64-B row

    // XCD-aware mapping: each XCD owns an 8m x 4n rectangle of 256-tiles
    const int xcd = blockIdx.x & 7;
    const int lid = blockIdx.x >> 3;         // 0..31
    const int bm = ((xcd >> 2) * 8 + (lid & 7)) * 256;
    const int bn = ((xcd & 3) * 4 + (lid >> 3)) * 256;

    // staging: 16-KB ks-half = 1024 chunks of 16B; thread owns c = t, t+512
    const int c0i = t, c1i = t + 512;
    const int r0 = c0i >> 2, r1 = c1i >> 2;              // row in tile 0..255
    const int lc0 = (c0i & 3) ^ ((r0 >> 1) & 3);         // logical chunk (global)
    const int lc1 = (c1i & 3) ^ ((r1 >> 1) & 3);
    const __bf16* a0p = A + (size_t)(bm + r0) * K + lc0 * 8;
    const __bf16* a1p = A + (size_t)(bm + r1) * K + lc1 * 8;
    const __bf16* b0p = B + (size_t)(bn + r0) * K + lc0 * 8;
    const __bf16* b1p = B + (size_t)(bn + r1) * K + lc1 * 8;

#define ST_A(kt, ks) do { \
    g2lds16(a0p + (size_t)(kt) * 64 + (ks) * 32, (char*)&sA[(kt) & 1][ks][0] + c0i * 16); \
    g2lds16(a1p + (size_t)(kt) * 64 + (ks) * 32, (char*)&sA[(kt) & 1][ks][0] + c1i * 16); } while (0)
#define ST_B(kt, ks) do { \
    g2lds16(b0p + (size_t)(kt) * 64 + (ks) * 32, (char*)&sB[(kt) & 1][ks][0] + c0i * 16); \
    g2lds16(b1p + (size_t)(kt) * 64 + (ks) * 32, (char*)&sB[(kt) & 1][ks][0] + c1i * 16); } while (0)
#define LDA(dst, fi, ks) dst = *(const bf16x8*)((const char*)&sA[slot][ks][0] + (wm + (fi) * 16 + l15) * 64 + cOff)
#define LDB(dst, ni, ks) dst = *(const bf16x8*)((const char*)&sB[slot][ks][0] + (wn + (ni) * 16 + l15) * 64 + cOff)
#define MFMA16(base, afr) do { \
    __builtin_amdgcn_s_setprio(1); \
    _Pragma("unroll") \
    for (int mi = 0; mi < 4; ++mi) \
        _Pragma("unroll") \
        for (int ni = 0; ni < 4; ++ni) \
            acc[(base) + mi][ni] = __builtin_amdgcn_mfma_f32_16x16x32_bf16( \
                afr[mi], bb[ni], acc[(base) + mi][ni], 0, 0, 0); \
    __builtin_amdgcn_s_setprio(0); } while (0)

    f32x4 acc[8][4] = {};

    // prologue: 12 loads; WAITVM(4) -> oldest 8 done = tile0 BOTH halves present
    ST_A(0, 0); ST_B(0, 0);
    ST_A(0, 1); ST_B(0, 1);
    ST_A(1, 0); ST_B(1, 0);
    WAITVM(4);
    BAR();

    #pragma unroll 1
    for (int kt = 0; kt < NKT; ++kt) {
        const int slot = kt & 1;
        bf16x8 aL[4], aH[4], bb[4];
        // ---- half 0 (ks0): 12 reads + E1/E2 stage + 32 MFMA, free-running
        #pragma unroll
        for (int mi = 0; mi < 4; ++mi) LDA(aL[mi], mi, 0);
        #pragma unroll
        for (int ni = 0; ni < 4; ++ni) LDB(bb[ni], ni, 0);
        #pragma unroll
        for (int mi = 0; mi < 4; ++mi) LDA(aH[mi], 4 + mi, 0);
        if (kt < NKT - 1) { ST_A(kt + 1, 1); ST_B(kt + 1, 1); }
        MFMA16(0, aL);
        MFMA16(4, aH);
        BAR();   // all waves' ks0 reads retired -> same-slot ks0 staging is safe
        // ---- half 1 (ks1): 12 reads + E3/E4 stage + 32 MFMA
        #pragma unroll
        for (int mi = 0; mi < 4; ++mi) LDA(aL[mi], mi, 1);
        #pragma unroll
        for (int ni = 0; ni < 4; ++ni) LDB(bb[ni], ni, 1);
        #pragma unroll
        for (int mi = 0; mi < 4; ++mi) LDA(aH[mi], 4 + mi, 1);
        if (kt < NKT - 2) { ST_A(kt + 2, 0); ST_B(kt + 2, 0); }
        MFMA16(0, aL);
        MFMA16(4, aH);
        if (kt < NKT - 2)       { WAITVM(4); }   // certifies kt+1 both halves
        else if (kt == NKT - 2) { WAITVM(0); }   // drain for final tile
        BAR();
    }

    // epilogue: C/D layout col=lane&15, row=(lane>>4)*4+reg (m89-verified);
    // ni-inner store order -> 256B contiguous per wave-row (WRITE_SIZE ~ideal)
    float bv[4];
    #pragma unroll
    for (int ni = 0; ni < 4; ++ni) bv[ni] = bias[bn + wn + ni * 16 + l15];
    #pragma unroll
    for (int mi = 0; mi < 8; ++mi) {
        #pragma unroll
        for (int r = 0; r < 4; ++r) {
            const int row = bm + wm + mi * 16 + lh * 4 + r;
            float* crow = C + (size_t)row * N + bn + wn + l15;
            #pragma unroll
            for (int ni = 0; ni < 4; ++ni)
                crow[ni * 16] = acc[mi][ni][r] + bv[ni];
        }
    }
#undef ST_A
#undef ST_B
#undef LDA
#undef LDB
#undef MFMA16
}

extern "C" void kernel_launch(void* const* d_in, const int* in_sizes, int n_in,
                              void* d_out, int out_size, void* d_ws, size_t ws_size,
                              hipStream_t stream) {
    const float* x    = (const float*)d_in[0];
    const float* c0   = (const float*)d_in[1];
    const float* c1   = (const float*)d_in[2];
    const float* c2   = (const float*)d_in[3];
    const float* c3   = (const float*)d_in[4];
    const float* bias = (const float*)d_in[5];
    float* out = (float*)d_out;

    __bf16* xb = (__bf16*)d_ws;                    // 4096*1024 bf16 = 8.39 MB
    __bf16* wt = xb + (size_t)4096 * 1024;         // 4096*1024 bf16 = 8.39 MB

    prep<<<3072, 256, 0, stream>>>(x, xb, c0, c1, c2, c3, wt);
    tt_gemm<<<256, 512, 0, stream>>>(xb, wt, bias, out);
}